// Round 9
// baseline (358.497 us; speedup 1.0000x reference)
//
#include <hip/hip_runtime.h>

typedef unsigned short u16;
typedef unsigned int   u32;
typedef unsigned long long u64;
typedef __attribute__((ext_vector_type(8))) short v8s;   // MFMA bf16 fragment
typedef __attribute__((ext_vector_type(8))) unsigned short v8u;
typedef __attribute__((ext_vector_type(4))) float v4f;

#define PI_F 3.14159265358979323846f

__device__ __forceinline__ float bf2f(u16 v){ u32 u = ((u32)v) << 16; return __builtin_bit_cast(float, u); }
__device__ __forceinline__ u16 f2bf(float f){
    u32 u = __builtin_bit_cast(u32, f);
    u32 r = (u + 0x7fffu + ((u >> 16) & 1u)) >> 16;
    return (u16)r;
}
// dtype discriminator: cell[0]=cell[1]=2/192. bf16 buffer -> first u32 halves equal.
__device__ __forceinline__ bool is_f32(const void* cellp){
    u32 u = *(const u32*)cellp;
    return ((u >> 16) != (u & 0xffffu));
}
__device__ __forceinline__ float ldin(const void* p, int i, bool f32){
    return f32 ? ((const float*)p)[i] : bf2f(((const u16*)p)[i]);
}
// MLP output column permutation pm (phys<-logical) inverse: given phys k, logical col.
__device__ __forceinline__ int pminv(int kp){
    int w2 = kp >> 6, p6 = kp & 63;
    return w2*64 + ((((p6>>5)&1)*2 + (p6&1)))*16 + ((p6>>1)&15);
}

// ---------------- workspace layout (bytes), total 5,440,000 ----------------
// MFMA weight streams pre-swizzled to wave-order 512-u16 chunks: lane offset lm*32+quad*8.
#define FEAT16_OFF 0        // [4][192][192][16] bf16 (9 used + 7 pad)  4,718,592
#define W2P_OFF   4718592   // [32 tiles][3 ks][512] bf16 swizzled MFMA1 W (98,304)
#define A1W_OFF   4816896   // [128][27] f32 (legacy, unused)
#define A1B_OFF   4830720   // [128] f32
#define A2W_OFF   4831232   // [3][9][128] f32 (legacy, unused)
#define A2B_OFF   4845056   // [3] f32 (pad)
#define PWF_OFF   4845312   // [128][2] f32 phase w
#define IBF_OFF   4846336   // [1027] f32 ib0..ib3 | ib4 (pad)
#define IWC_OFF   4850688   // [4 layer][4 wv][8 ks][4 nt][512] bf16 swizzled MLP W, k-rows perm (524,288)
#define CBP_OFF   5376512   // [512] f32 permuted-col bias for MFMA1
#define W4P_OFF   5378560   // [8 ks][512] bf16 swizzled final-layer W, k-rows perm (8,192)
#define W1SW_OFF  5386752   // [2 h][4 nt][2 ks][512] bf16 swizzled conv1 W (16,384)
#define W2SW_OFF  5403136   // [2 h][9 tap][2 ks][512] bf16 swizzled conv2 W (36,864)

// ---------------- pack/convert kernel (dtype-adaptive) ----------------
__global__ __launch_bounds__(256) void k_pack(
    const void* cw, const void* fw, const void* a1w, const void* a1b,
    const void* a2w, const void* a2b, const void* cb, const void* fb, const void* pwp,
    const void* iw0, const void* ib0, const void* iw1, const void* ib1,
    const void* iw2, const void* ib2, const void* iw3, const void* ib3,
    const void* iw4, const void* ib4, const void* cellp, char* ws){
    bool f32 = is_f32(cellp);
    u16*   w2p  = (u16*)(ws + W2P_OFF);
    float* a1wf = (float*)(ws + A1W_OFF);
    float* a1bf = (float*)(ws + A1B_OFF);
    float* a2wf = (float*)(ws + A2W_OFF);
    float* a2bf = (float*)(ws + A2B_OFF);
    float* pwf  = (float*)(ws + PWF_OFF);
    float* ibf  = (float*)(ws + IBF_OFF);
    u16*   iwc  = (u16*)(ws + IWC_OFF);
    float* cbp  = (float*)(ws + CBP_OFF);
    u16*   w4p  = (u16*)(ws + W4P_OFF);
    u16*   w1sw = (u16*)(ws + W1SW_OFF);
    u16*   w2sw = (u16*)(ws + W2SW_OFF);

    int t = blockIdx.x*256 + threadIdx.x;
    if (t < 49152){
        // dest: [tile 32][ks 3][lm 16][quad 4][jj 8]
        int c = t >> 9, rem = t & 511;
        int tile = c/3, ks = c%3;
        int lm = rem >> 5, r2 = rem & 31, quad = r2 >> 3, jj = r2 & 7;
        int n = tile*16 + lm;          // permuted column
        int r = quad*8 + jj;           // k within row-chunk: 27 used + 5 pad
        u16 v = 0;
        if (r < 27){
            int pix = r/9, ch = r%9;
            int tap = ks*3 + pix;      // gather row ks, pixel pix
            int src = ch*9 + tap;
            if (n < 256) v = f2bf(ldin(cw, n*81 + src, f32));
            else { int u_ = n - 256; int tt = u_ >> 4, nn = u_ & 15;
                   int f = 2*((tt>>1)*16 + nn) + (tt & 1);
                   v = f2bf(ldin(fw, f*81 + src, f32)); }
        }
        w2p[t] = v; return;
    }
    t -= 49152;
    if (t < 3456){ a1wf[t] = ldin(a1w, t, f32); return; }
    t -= 3456;
    if (t < 128){ a1bf[t] = ldin(a1b, t, f32); return; }
    t -= 128;
    if (t < 3456){
        int o = t/1152, r = t%1152, c = r/9, tap = r%9;
        a2wf[(o*9 + tap)*128 + c] = ldin(a2w, t, f32); return;
    }
    t -= 3456;
    if (t < 3){ a2bf[t] = ldin(a2b, t, f32); return; }
    t -= 3;
    if (t < 256){ pwf[t] = ldin(pwp, t, f32); return; }
    t -= 256;
    if (t < 1027){
        const void* src = (t < 256) ? ib0 : (t < 512) ? ib1 : (t < 768) ? ib2 : (t < 1024) ? ib3 : ib4;
        int idx = (t < 1024) ? (t & 255) : (t - 1024);
        ibf[t] = ldin(src, idx, f32); return;
    }
    t -= 1027;
    if (t < 262144){
        // dest: [l 4][wv 4][ks 8][nt 4][lm 16][quad 4][jj 8]; k-rows permuted to match X phys layout
        int c = t >> 9, rem = t & 511;
        int lm = rem >> 5, r2 = rem & 31, quad = r2 >> 3, jj = r2 & 7;
        int nt = c & 3, ks = (c >> 2) & 7, wv = (c >> 5) & 3, l = c >> 7;
        int col = wv*64 + nt*16 + lm;
        int kp = ks*32 + quad*8 + jj;
        int kl;
        if (l == 0) kl = (kp & 1) ? 128 + (kp >> 1) : (kp >> 1);   // p0inv: cos/sin interleave
        else        kl = pminv(kp);                                 // pm inverse
        const void* src = (l==0) ? iw0 : (l==1) ? iw1 : (l==2) ? iw2 : iw3;
        iwc[t] = f2bf(ldin(src, col*256 + kl, f32)); return;
    }
    t -= 262144;
    if (t < 768){ return; }
    t -= 768;
    if (t < 512){
        float v;
        if (t < 256) v = ldin(cb, t, f32);
        else { int u_ = t - 256; int tt = u_ >> 4, nn = u_ & 15;
               int f = 2*((tt>>1)*16 + nn) + (tt & 1); v = ldin(fb, f, f32); }
        cbp[t] = v; return;
    }
    t -= 512;
    if (t < 4096){
        // dest: [ks 8][lm 16][quad 4][jj 8]; k-rows permuted by pm (layer-3 output perm)
        int ks = t >> 9, rem = t & 511;
        int lm = rem >> 5, r2 = rem & 31, quad = r2 >> 3, jj = r2 & 7;
        int kp = ks*32 + quad*8 + jj;
        int kl = pminv(kp);
        w4p[t] = (lm < 3) ? f2bf(ldin(iw4, lm*256 + kl, f32)) : (u16)0;
        return;
    }
    t -= 4096;
    if (t < 8192){
        // conv1 swizzle: [h 2][nt 4][ks 2][512]; K layout ks0: jr0@0..15, jr1@16..31; ks1: jr2@0..11
        int c = t >> 9, rem = t & 511;
        int lm = rem >> 5, r2 = rem & 31, quad = r2 >> 3, jj = r2 & 7;
        int h = c >> 3, nt = (c & 7) >> 1, ks = c & 1;
        int ch = h*64 + nt*16 + lm;
        int kk = quad*8 + jj;
        u16 v = 0;
        int jr = -1, r = 0;
        if (ks == 0){ jr = kk >> 4; r = kk & 15; }
        else if (kk < 16){ jr = 2; r = kk; }
        if (jr >= 0 && r < 12){
            int px = r >> 2, ci = r & 3;
            if (ci < 3) v = f2bf(ldin(a1w, ch*27 + ci*9 + jr*3 + px, f32));
        }
        w1sw[t] = v; return;
    }
    t -= 8192;
    if (t < 18432){
        // conv2 swizzle: [h 2][tap 9][ks 2][512]; k = ch within half
        int c = t >> 9, rem = t & 511;
        int lm = rem >> 5, r2 = rem & 31, quad = r2 >> 3, jj = r2 & 7;
        int h = c / 18, tap = (c % 18) >> 1, ks = c & 1;
        int k = ks*32 + quad*8 + jj;
        int ch = h*64 + k;
        u16 v = 0;
        if (lm < 3) v = f2bf(ldin(a2w, lm*1152 + ch*9 + tap, f32));
        w2sw[t] = v; return;
    }
}

// ---------------- MFMA adapter: conv1(3->128)+sin, conv2(128->3)+sin, build feat16 ----------------
__global__ __launch_bounds__(256, 3) void k_adapter(const void* __restrict__ inp, const void* __restrict__ score,
                                                    const void* __restrict__ cellp, char* __restrict__ ws){
    __shared__ __attribute__((aligned(16))) char smem[46480];
    bool f32 = is_f32(cellp);
    const float* a1bf = (const float*)(ws + A1B_OFF);
    const float* a2bf = (const float*)(ws + A2B_OFF);
    const u16*   w1sw = (const u16*)(ws + W1SW_OFF);
    const u16*   w2sw = (const u16*)(ws + W2SW_OFF);
    u16* feat16 = (u16*)(ws + FEAT16_OFF);

    int blk = blockIdx.x; int b = blk/288; int rem = blk%288;
    int ty0 = (rem/12)*8, tx0 = (rem%12)*16;
    int tid = threadIdx.x;
    u16* S   = (u16*)smem;
    u16* A   = (u16*)(smem + 1920);
    u16* hid = (u16*)(smem + 22000);

    if (tid < 240) ((u64*)smem)[tid] = 0ULL;
    __syncthreads();
    #pragma unroll 1
    for (int e = tid; e < 720; e += 256){
        int ci = e/240, r2 = e%240, hy = r2/20, hx = r2%20;
        int gy = ty0 - 2 + hy, gx = tx0 - 2 + hx;
        if (gy >= 0 && gy < 192 && gx >= 0 && gx < 192)
            S[(hy*20+hx)*4 + ci] = f2bf(ldin(inp, (b*3+ci)*36864 + gy*192 + gx, f32));
    }
    __syncthreads();
    #pragma unroll 1
    for (int p = tid; p < 193; p += 256){
        u64* drow = (u64*)(A + p*52);
        if (p < 180){
            int hy = p/18, hx = p%18;
            #pragma unroll
            for (int jr = 0; jr < 3; ++jr){
                const u64* srow = (const u64*)(S + ((hy+jr)*20 + hx)*4);
                u64 v0 = srow[0], v1 = srow[1], v2 = srow[2];
                drow[jr*4+0] = v0; drow[jr*4+1] = v1; drow[jr*4+2] = v2; drow[jr*4+3] = 0ULL;
            }
            drow[12] = 0ULL;
        } else {
            #pragma unroll
            for (int k = 0; k < 13; ++k) drow[k] = 0ULL;
        }
    }
    __syncthreads();

    const int wv = tid >> 6, ln = tid & 63;
    const int lm = ln & 15, quad = ln >> 4;
    const int laneoff = lm*32 + quad*8;

    float bias2 = (lm < 3) ? a2bf[lm] : 0.f;
    v4f acc2[2];
    acc2[0] = (v4f){bias2,bias2,bias2,bias2};
    acc2[1] = acc2[0];

    #pragma unroll 1
    for (int h = 0; h < 2; ++h){
        float bias1 = a1bf[h*64 + wv*16 + lm];
        v8s B0 = *(const v8s*)(w1sw + (h*8 + wv*2 + 0)*512 + laneoff);
        v8s B1 = *(const v8s*)(w1sw + (h*8 + wv*2 + 1)*512 + laneoff);
        #pragma unroll 4
        for (int mt = 0; mt < 12; ++mt){
            const u16* ar = A + (mt*16 + lm)*52 + quad*8;
            v8s a0 = *(const v8s*)(ar);
            v8s a1 = *(const v8s*)(ar + 32);
            v4f c = (v4f){bias1,bias1,bias1,bias1};
            c = __builtin_amdgcn_mfma_f32_16x16x32_bf16(a0, B0, c, 0,0,0);
            c = __builtin_amdgcn_mfma_f32_16x16x32_bf16(a1, B1, c, 0,0,0);
            #pragma unroll
            for (int r = 0; r < 4; ++r){
                int px = mt*16 + quad*4 + r;
                if (px < 180){
                    int hy = px/18, hx = px - hy*18;
                    int gy = ty0 - 1 + hy, gx = tx0 - 1 + hx;
                    bool ok = (gy >= 0) & (gy < 192) & (gx >= 0) & (gx < 192);
                    hid[px*68 + wv*16 + lm] = ok ? f2bf(__sinf(c[r])) : (u16)0;
                }
            }
        }
        __syncthreads();
        #pragma unroll 2
        for (int tap = 0; tap < 9; ++tap){
            int ty = tap/3, tx = tap%3;
            v8s Bt0 = *(const v8s*)(w2sw + ((h*9 + tap)*2 + 0)*512 + laneoff);
            v8s Bt1 = *(const v8s*)(w2sw + ((h*9 + tap)*2 + 1)*512 + laneoff);
            #pragma unroll
            for (int i = 0; i < 2; ++i){
                int py = wv*2 + i;
                const u16* hrow = hid + ((py+ty)*18 + lm + tx)*68;
                v8s a0 = *(const v8s*)(hrow + quad*8);
                v8s a1 = *(const v8s*)(hrow + 32 + quad*8);
                acc2[i] = __builtin_amdgcn_mfma_f32_16x16x32_bf16(a0, Bt0, acc2[i], 0,0,0);
                acc2[i] = __builtin_amdgcn_mfma_f32_16x16x32_bf16(a1, Bt1, acc2[i], 0,0,0);
            }
        }
        __syncthreads();
    }
    u16* out3 = S;
    if (lm < 3){
        #pragma unroll
        for (int i = 0; i < 2; ++i)
            #pragma unroll
            for (int r = 0; r < 4; ++r){
                int m = (wv*2 + i)*16 + quad*4 + r;
                out3[m*4 + lm] = f2bf(__sinf(acc2[i][r]));
            }
    }
    __syncthreads();
    if (tid < 128){
        int py = tid >> 4, px = tid & 15;
        int gy = ty0 + py, gx = tx0 + px;
        int pi = b*3*36864 + gy*192 + gx;
        v8u lo, hi;
        lo[0] = f2bf(ldin(inp, pi, f32));
        lo[1] = f2bf(ldin(inp, pi + 36864, f32));
        lo[2] = f2bf(ldin(inp, pi + 2*36864, f32));
        lo[3] = f2bf(ldin(score, pi, f32));
        lo[4] = f2bf(ldin(score, pi + 36864, f32));
        lo[5] = f2bf(ldin(score, pi + 2*36864, f32));
        lo[6] = out3[tid*4 + 0];
        lo[7] = out3[tid*4 + 1];
        hi[0] = out3[tid*4 + 2];
        hi[1]=hi[2]=hi[3]=hi[4]=hi[5]=hi[6]=hi[7]=0;
        u16* fp = feat16 + ((b*192 + gy)*192 + gx)*16;
        *(v8u*)fp = lo;
        *(v8u*)(fp + 8) = hi;
    }
}

// ---------------- mega kernel ----------------
// LDS 32768B. X: 32 chunks of [64 q][16B], chunk C at 16B-unit index C*64 + (q ^ (C&3)).
// Columns stored physically permuted (p0 for layer-0 input, pm between MLP layers); W k-rows
// pre-permuted in k_pack to match. u32-packed writes -> 2-way bank conflicts (free).
// Apat ALIASED at [0,12288); meta in registers. (256,3): (256,4)+ spills (R7/R8 evidence).
__global__ __launch_bounds__(256, 3) void k_mega(const char* __restrict__ ws,
                                                 const void* __restrict__ inp,
                                                 const void* __restrict__ coord,
                                                 const void* __restrict__ cellp,
                                                 void* __restrict__ out){
    __shared__ __attribute__((aligned(16))) char smem[32768];
    bool f32 = is_f32(cellp);
    const u16*   feat16 = (const u16*)(ws + FEAT16_OFF);
    const u16*   w2p    = (const u16*)(ws + W2P_OFF);
    const float* pwf    = (const float*)(ws + PWF_OFF);
    const float* ibf    = (const float*)(ws + IBF_OFF);
    const u16*   iwc    = (const u16*)(ws + IWC_OFF);
    const float* cbp    = (const float*)(ws + CBP_OFF);
    const u16*   w4p    = (const u16*)(ws + W4P_OFF);

    const int tid = threadIdx.x;
    const int qg0 = blockIdx.x * 64;
    const int b = qg0 / 36864;

    // ---- phase 1: gather patches into Apat (aliased at smem[0,12288)) ----
    {
        int q = tid >> 2, j = tid & 3;
        int qg = qg0 + q;
        u16* ap = (u16*)smem;
        float c0 = ldin(coord, qg*2, f32), c1 = ldin(coord, qg*2+1, f32);
        const float e = 1e-6f;
        float cy = fminf(fmaxf(c0, -1.f+e), 1.f-e);
        float cx = fminf(fmaxf(c1, -1.f+e), 1.f-e);
        int iy = (int)rintf(((cy+1.f)*192.f-1.f)*0.5f); iy = min(max(iy,0),191);
        int ix = (int)rintf(((cx+1.f)*192.f-1.f)*0.5f); ix = min(max(ix,0),191);
        if (j < 3){
            int yy = iy - 1 + j;
            bool yok = (yy >= 0) & (yy <= 191);
            union { u16 a[32]; v8u v[4]; } buf;
            #pragma unroll
            for (int c = 0; c < 32; ++c) buf.a[c] = 0;
            if (yok){
                const u16* base = feat16 + ((b*192 + yy)*192)*16;
                #pragma unroll
                for (int pix = 0; pix < 3; ++pix){
                    int xx = ix - 1 + pix;
                    if (xx >= 0 && xx <= 191){
                        const u16* s = base + xx*16;
                        v8u v = *(const v8u*)s;
                        u16 c8 = s[8];
                        #pragma unroll
                        for (int c = 0; c < 8; ++c) buf.a[pix*9+c] = v[c];
                        buf.a[pix*9+8] = c8;
                    }
                }
            }
            u16* dst = ap + q*96 + j*32;
            *(v8u*)(dst)      = buf.v[0];
            *(v8u*)(dst + 8)  = buf.v[1];
            *(v8u*)(dst + 16) = buf.v[2];
            *(v8u*)(dst + 24) = buf.v[3];
        }
    }
    __syncthreads();

    const int wv = tid >> 6, ln = tid & 63;
    const int lm = ln & 15, quad = ln >> 4;
    const int laneoff = lm*32 + quad*8;
    u32* X32 = (u32*)smem;

    // ---- per-lane meta (registers) ----
    float4 mm[4];
    #pragma unroll
    for (int r = 0; r < 4; ++r){
        int qg = qg0 + wv*16 + quad*4 + r;
        float c0 = ldin(coord, qg*2, f32), c1 = ldin(coord, qg*2+1, f32);
        const float e = 1e-6f;
        float cy = fminf(fmaxf(c0, -1.f+e), 1.f-e);
        float cx = fminf(fmaxf(c1, -1.f+e), 1.f-e);
        int iy = (int)rintf(((cy+1.f)*192.f-1.f)*0.5f); iy = min(max(iy,0),191);
        int ix = (int)rintf(((cx+1.f)*192.f-1.f)*0.5f); ix = min(max(ix,0),191);
        float qy = -1.f + (2.f*iy + 1.f)/192.f;
        float qx = -1.f + (2.f*ix + 1.f)/192.f;
        mm[r].x = (c0 - qy)*192.f; mm[r].y = (c1 - qx)*192.f;
        mm[r].z = ldin(cellp, qg*2, f32)*192.f; mm[r].w = ldin(cellp, qg*2+1, f32)*192.f;
    }

    // ---- phase 2+3: wave-owns-rows MFMA1, fused trig+modulation, packed u32 X writes ----
    {
        v8s afr[3];
        #pragma unroll
        for (int ks = 0; ks < 3; ++ks)
            afr[ks] = *(const v8s*)(smem + ((wv*16 + lm)*96 + ks*32 + quad*8)*2);
        float p0[8], p1[8];
        #pragma unroll
        for (int g = 0; g < 8; ++g){
            int j = g*16 + lm;
            p0[g] = pwf[2*j]; p1[g] = pwf[2*j+1];
        }
        v8s Bc0[3], Bc1[3], Bf0[3], Bf1[3];
        {
            const u16* p;
            p = w2p + 0*1536  + laneoff; Bc0[0]=*(const v8s*)p; Bc0[1]=*(const v8s*)(p+512); Bc0[2]=*(const v8s*)(p+1024);
            p = w2p + 8*1536  + laneoff; Bc1[0]=*(const v8s*)p; Bc1[1]=*(const v8s*)(p+512); Bc1[2]=*(const v8s*)(p+1024);
            p = w2p + 16*1536 + laneoff; Bf0[0]=*(const v8s*)p; Bf0[1]=*(const v8s*)(p+512); Bf0[2]=*(const v8s*)(p+1024);
            p = w2p + 17*1536 + laneoff; Bf1[0]=*(const v8s*)p; Bf1[1]=*(const v8s*)(p+512); Bf1[2]=*(const v8s*)(p+1024);
        }
        __syncthreads();   // Apat consumed; X region free
        #pragma unroll 1
        for (int g = 0; g < 8; ++g){
            float bb0 = cbp[g*16+lm], bb1 = cbp[(8+g)*16+lm];
            float bb2 = cbp[(16+2*g)*16+lm], bb3 = cbp[(17+2*g)*16+lm];
            v4f a0 = (v4f){bb0,bb0,bb0,bb0};
            v4f a1 = (v4f){bb1,bb1,bb1,bb1};
            v4f a2 = (v4f){bb2,bb2,bb2,bb2};
            v4f a3 = (v4f){bb3,bb3,bb3,bb3};
            #pragma unroll
            for (int ks = 0; ks < 3; ++ks){
                a0 = __builtin_amdgcn_mfma_f32_16x16x32_bf16(afr[ks], Bc0[ks], a0, 0,0,0);
                a1 = __builtin_amdgcn_mfma_f32_16x16x32_bf16(afr[ks], Bc1[ks], a1, 0,0,0);
                a2 = __builtin_amdgcn_mfma_f32_16x16x32_bf16(afr[ks], Bf0[ks], a2, 0,0,0);
                a3 = __builtin_amdgcn_mfma_f32_16x16x32_bf16(afr[ks], Bf1[ks], a3, 0,0,0);
            }
            if (g < 7){
                const u16* p;
                p = w2p + (g+1)*1536    + laneoff; Bc0[0]=*(const v8s*)p; Bc0[1]=*(const v8s*)(p+512); Bc0[2]=*(const v8s*)(p+1024);
                p = w2p + (9+g)*1536    + laneoff; Bc1[0]=*(const v8s*)p; Bc1[1]=*(const v8s*)(p+512); Bc1[2]=*(const v8s*)(p+1024);
                p = w2p + (18+2*g)*1536 + laneoff; Bf0[0]=*(const v8s*)p; Bf0[1]=*(const v8s*)(p+512); Bf0[2]=*(const v8s*)(p+1024);
                p = w2p + (19+2*g)*1536 + laneoff; Bf1[0]=*(const v8s*)p; Bf1[1]=*(const v8s*)(p+512); Bf1[2]=*(const v8s*)(p+1024);
            }
            // X write: logical cols j (coef*cos), 128+j (coef*sin) -> phys 2j, 2j+1 packed u32
            int c2 = g*16 + lm;            // u32 column index
            int C = c2 >> 2, sw = lm >> 2; // C&3 == lm>>2
            int abase = C*256 + (lm & 3);
            #pragma unroll
            for (int r = 0; r < 4; ++r){
                float qf = a2[r]*mm[r].x + a3[r]*mm[r].y + mm[r].z*p0[g] + mm[r].w*p1[g];
                float sn, cs;
                __sincosf(PI_F * qf, &sn, &cs);
                int q = wv*16 + quad*4 + r;
                u32 val = (u32)f2bf(a0[r] * cs) | ((u32)f2bf(a1[r] * sn) << 16);
                X32[abase + ((q ^ sw) << 2)] = val;
            }
        }
    }
    __syncthreads();

    // ---- phase 5: 4 hidden layers 256->256 + relu, in-place X, depth-2 W prefetch ----
    #pragma unroll 1
    for (int l = 0; l < 4; ++l){
        const u16* Wb = iwc + (l*4 + wv)*16384 + laneoff;
        v4f acc[4][4];
        #pragma unroll
        for (int nt = 0; nt < 4; ++nt){
            float bv = ibf[l*256 + wv*64 + nt*16 + lm];
            #pragma unroll
            for (int mt = 0; mt < 4; ++mt) acc[nt][mt] = (v4f){bv,bv,bv,bv};
        }
        v8s bw[2][4];
        #pragma unroll
        for (int nt = 0; nt < 4; ++nt){
            bw[0][nt] = *(const v8s*)(Wb + (0*4 + nt)*512);
            bw[1][nt] = *(const v8s*)(Wb + (1*4 + nt)*512);
        }
        #pragma unroll
        for (int ks = 0; ks < 8; ++ks){
            v8s a[4];
            #pragma unroll
            for (int mt = 0; mt < 4; ++mt)
                a[mt] = *(const v8s*)((const char*)smem +
                        ((((ks*4 + quad)*64) + ((mt*16 + lm) ^ quad)) << 4));
            v8s nb[4];
            if (ks < 6){
                #pragma unroll
                for (int nt = 0; nt < 4; ++nt)
                    nb[nt] = *(const v8s*)(Wb + ((ks+2)*4 + nt)*512);
            }
            #pragma unroll
            for (int nt = 0; nt < 4; ++nt)
                #pragma unroll
                for (int mt = 0; mt < 4; ++mt)
                    acc[nt][mt] = __builtin_amdgcn_mfma_f32_16x16x32_bf16(a[mt], bw[ks&1][nt], acc[nt][mt], 0,0,0);
            if (ks < 6){
                #pragma unroll
                for (int nt = 0; nt < 4; ++nt) bw[ks&1][nt] = nb[nt];
            }
        }
        __syncthreads();   // all reads of X complete
        // epilogue: pm-permuted packed u32 writes (nt pairs interleaved)
        #pragma unroll
        for (int h = 0; h < 2; ++h){
            int c2 = wv*32 + h*16 + lm;
            int C = c2 >> 2, sw = lm >> 2;   // C&3 == lm>>2
            int abase = C*256 + (lm & 3);
            #pragma unroll
            for (int mt = 0; mt < 4; ++mt)
                #pragma unroll
                for (int r = 0; r < 4; ++r){
                    int q = mt*16 + quad*4 + r;
                    u32 lo16 = f2bf(fmaxf(acc[2*h+0][mt][r], 0.f));
                    u32 hi16 = f2bf(fmaxf(acc[2*h+1][mt][r], 0.f));
                    X32[abase + ((q ^ sw) << 2)] = lo16 | (hi16 << 16);
                }
        }
        __syncthreads();
    }

    // ---- phase 6: final 256->3 via MFMA (wave = row-tile) + bilinear ----
    {
        float bv = (lm < 3) ? ibf[1024 + lm] : 0.f;
        v4f accf = (v4f){bv,bv,bv,bv};
        v8s bA = *(const v8s*)(w4p + laneoff);
        #pragma unroll
        for (int ks = 0; ks < 8; ++ks){
            v8s a = *(const v8s*)((const char*)smem +
                    ((((ks*4 + quad)*64) + ((wv*16 + lm) ^ quad)) << 4));
            v8s bN;
            if (ks < 7) bN = *(const v8s*)(w4p + (ks+1)*512 + laneoff);
            accf = __builtin_amdgcn_mfma_f32_16x16x32_bf16(a, bA, accf, 0,0,0);
            bA = bN;
        }
        if (lm < 3){
            #pragma unroll
            for (int r = 0; r < 4; ++r){
                int q = wv*16 + quad*4 + r;
                int qg = qg0 + q;
                float c0 = ldin(coord, qg*2, f32), c1 = ldin(coord, qg*2+1, f32);
                float fy = ((c0 + 1.f)*192.f - 1.f)*0.5f;
                float fx = ((c1 + 1.f)*192.f - 1.f)*0.5f;
                float y0 = floorf(fy), x0 = floorf(fx);
                float wy = fy - y0, wx = fx - x0;
                int y0i = (int)fminf(fmaxf(y0, 0.f), 191.f);
                int y1i = (int)fminf(fmaxf(y0 + 1.f, 0.f), 191.f);
                int x0i = (int)fminf(fmaxf(x0, 0.f), 191.f);
                int x1i = (int)fminf(fmaxf(x0 + 1.f, 0.f), 191.f);
                int ibase = (b*3 + lm)*36864;
                float v00 = ldin(inp, ibase + y0i*192 + x0i, f32);
                float v01 = ldin(inp, ibase + y0i*192 + x1i, f32);
                float v10 = ldin(inp, ibase + y1i*192 + x0i, f32);
                float v11 = ldin(inp, ibase + y1i*192 + x1i, f32);
                float bil = v00*(1.f-wy)*(1.f-wx) + v01*(1.f-wy)*wx + v10*wy*(1.f-wx) + v11*wy*wx;
                float val = accf[r] + bil;
                if (f32) ((float*)out)[qg*3 + lm] = val;
                else     ((u16*)out)[qg*3 + lm] = f2bf(val);
            }
        }
    }
}

extern "C" void kernel_launch(void* const* d_in, const int* in_sizes, int n_in,
                              void* d_out, int out_size, void* d_ws, size_t ws_size,
                              hipStream_t stream){
    (void)in_sizes; (void)n_in; (void)out_size; (void)ws_size;
    const void* inp   = d_in[0];
    const void* score = d_in[1];
    const void* coord = d_in[2];
    const void* cellp = d_in[3];
    const void* cw    = d_in[4];
    const void* cb    = d_in[5];
    const void* fw    = d_in[6];
    const void* fb    = d_in[7];
    const void* pw    = d_in[8];
    const void* a1w   = d_in[9];
    const void* a1b   = d_in[10];
    const void* a2w   = d_in[11];
    const void* a2b   = d_in[12];
    const void* iw0   = d_in[13];
    const void* ib0   = d_in[14];
    const void* iw1   = d_in[15];
    const void* ib1   = d_in[16];
    const void* iw2   = d_in[17];
    const void* ib2   = d_in[18];
    const void* iw3   = d_in[19];
    const void* ib3   = d_in[20];
    const void* iw4   = d_in[21];
    const void* ib4   = d_in[22];
    char* ws = (char*)d_ws;

    hipLaunchKernelGGL(k_pack, dim3(1374), dim3(256), 0, stream,
                       cw, fw, a1w, a1b, a2w, a2b, cb, fb, pw,
                       iw0, ib0, iw1, ib1, iw2, ib2, iw3, ib3, iw4, ib4,
                       cellp, ws);
    hipLaunchKernelGGL(k_adapter, dim3(1152), dim3(256), 0, stream, inp, score, cellp, ws);
    hipLaunchKernelGGL(k_mega, dim3(2304), dim3(256), 0, stream, (const char*)ws, inp, coord, cellp, d_out);
}

// Round 10
// 344.459 us; speedup vs baseline: 1.0408x; 1.0408x over previous
//
#include <hip/hip_runtime.h>

typedef unsigned short u16;
typedef unsigned int   u32;
typedef unsigned long long u64;
typedef __attribute__((ext_vector_type(8))) short v8s;   // MFMA bf16 fragment
typedef __attribute__((ext_vector_type(8))) unsigned short v8u;
typedef __attribute__((ext_vector_type(4))) float v4f;

#define PI_F 3.14159265358979323846f

__device__ __forceinline__ float bf2f(u16 v){ u32 u = ((u32)v) << 16; return __builtin_bit_cast(float, u); }
__device__ __forceinline__ u16 f2bf(float f){
    u32 u = __builtin_bit_cast(u32, f);
    u32 r = (u + 0x7fffu + ((u >> 16) & 1u)) >> 16;
    return (u16)r;
}
// dtype discriminator: cell[0]=cell[1]=2/192. bf16 buffer -> first u32 halves equal.
__device__ __forceinline__ bool is_f32(const void* cellp){
    u32 u = *(const u32*)cellp;
    return ((u >> 16) != (u & 0xffffu));
}
__device__ __forceinline__ float ldin(const void* p, int i, bool f32){
    return f32 ? ((const float*)p)[i] : bf2f(((const u16*)p)[i]);
}
// MLP output column permutation pm (phys<-logical) inverse: given phys k, logical col.
__device__ __forceinline__ int pminv(int kp){
    int w2 = kp >> 6, p6 = kp & 63;
    return w2*64 + ((((p6>>5)&1)*2 + (p6&1)))*16 + ((p6>>1)&15);
}

// ---------------- workspace layout (bytes), total 5,440,000 ----------------
// MFMA weight streams pre-swizzled to wave-order 512-u16 chunks: lane offset lm*32+quad*8.
#define FEAT16_OFF 0        // [4][192][192][16] bf16 (9 used + 7 pad)  4,718,592
#define W2P_OFF   4718592   // [32 tiles][3 ks][512] bf16 swizzled MFMA1 W (98,304)
#define A1W_OFF   4816896   // [128][27] f32 (legacy, unused)
#define A1B_OFF   4830720   // [128] f32
#define A2W_OFF   4831232   // [3][9][128] f32 (legacy, unused)
#define A2B_OFF   4845056   // [3] f32 (pad)
#define PWF_OFF   4845312   // [128][2] f32 phase w
#define IBF_OFF   4846336   // [1027] f32 ib0..ib3 | ib4 (pad)
#define IWC_OFF   4850688   // [4 layer][4 wv][8 ks][4 nt][512] bf16 swizzled MLP W, k-rows perm (524,288)
#define CBP_OFF   5376512   // [512] f32 permuted-col bias for MFMA1
#define W4P_OFF   5378560   // [8 ks][512] bf16 swizzled final-layer W, k-rows perm (8,192)
#define W1SW_OFF  5386752   // [2 h][4 nt][2 ks][512] bf16 swizzled conv1 W (16,384)
#define W2SW_OFF  5403136   // [2 h][9 tap][2 ks][512] bf16 swizzled conv2 W (36,864)

// ---------------- pack/convert kernel (dtype-adaptive) ----------------
__global__ __launch_bounds__(256) void k_pack(
    const void* cw, const void* fw, const void* a1w, const void* a1b,
    const void* a2w, const void* a2b, const void* cb, const void* fb, const void* pwp,
    const void* iw0, const void* ib0, const void* iw1, const void* ib1,
    const void* iw2, const void* ib2, const void* iw3, const void* ib3,
    const void* iw4, const void* ib4, const void* cellp, char* ws){
    bool f32 = is_f32(cellp);
    u16*   w2p  = (u16*)(ws + W2P_OFF);
    float* a1wf = (float*)(ws + A1W_OFF);
    float* a1bf = (float*)(ws + A1B_OFF);
    float* a2wf = (float*)(ws + A2W_OFF);
    float* a2bf = (float*)(ws + A2B_OFF);
    float* pwf  = (float*)(ws + PWF_OFF);
    float* ibf  = (float*)(ws + IBF_OFF);
    u16*   iwc  = (u16*)(ws + IWC_OFF);
    float* cbp  = (float*)(ws + CBP_OFF);
    u16*   w4p  = (u16*)(ws + W4P_OFF);
    u16*   w1sw = (u16*)(ws + W1SW_OFF);
    u16*   w2sw = (u16*)(ws + W2SW_OFF);

    int t = blockIdx.x*256 + threadIdx.x;
    if (t < 49152){
        // dest: [tile 32][ks 3][lm 16][quad 4][jj 8]
        int c = t >> 9, rem = t & 511;
        int tile = c/3, ks = c%3;
        int lm = rem >> 5, r2 = rem & 31, quad = r2 >> 3, jj = r2 & 7;
        int n = tile*16 + lm;          // permuted column
        int r = quad*8 + jj;           // k within row-chunk: 27 used + 5 pad
        u16 v = 0;
        if (r < 27){
            int pix = r/9, ch = r%9;
            int tap = ks*3 + pix;      // gather row ks, pixel pix
            int src = ch*9 + tap;
            if (n < 256) v = f2bf(ldin(cw, n*81 + src, f32));
            else { int u_ = n - 256; int tt = u_ >> 4, nn = u_ & 15;
                   int f = 2*((tt>>1)*16 + nn) + (tt & 1);
                   v = f2bf(ldin(fw, f*81 + src, f32)); }
        }
        w2p[t] = v; return;
    }
    t -= 49152;
    if (t < 3456){ a1wf[t] = ldin(a1w, t, f32); return; }
    t -= 3456;
    if (t < 128){ a1bf[t] = ldin(a1b, t, f32); return; }
    t -= 128;
    if (t < 3456){
        int o = t/1152, r = t%1152, c = r/9, tap = r%9;
        a2wf[(o*9 + tap)*128 + c] = ldin(a2w, t, f32); return;
    }
    t -= 3456;
    if (t < 3){ a2bf[t] = ldin(a2b, t, f32); return; }
    t -= 3;
    if (t < 256){ pwf[t] = ldin(pwp, t, f32); return; }
    t -= 256;
    if (t < 1027){
        const void* src = (t < 256) ? ib0 : (t < 512) ? ib1 : (t < 768) ? ib2 : (t < 1024) ? ib3 : ib4;
        int idx = (t < 1024) ? (t & 255) : (t - 1024);
        ibf[t] = ldin(src, idx, f32); return;
    }
    t -= 1027;
    if (t < 262144){
        // dest: [l 4][wv 4][ks 8][nt 4][lm 16][quad 4][jj 8]; k-rows permuted to match X phys layout
        int c = t >> 9, rem = t & 511;
        int lm = rem >> 5, r2 = rem & 31, quad = r2 >> 3, jj = r2 & 7;
        int nt = c & 3, ks = (c >> 2) & 7, wv = (c >> 5) & 3, l = c >> 7;
        int col = wv*64 + nt*16 + lm;
        int kp = ks*32 + quad*8 + jj;
        int kl;
        if (l == 0) kl = (kp & 1) ? 128 + (kp >> 1) : (kp >> 1);   // p0inv: cos/sin interleave
        else        kl = pminv(kp);                                 // pm inverse
        const void* src = (l==0) ? iw0 : (l==1) ? iw1 : (l==2) ? iw2 : iw3;
        iwc[t] = f2bf(ldin(src, col*256 + kl, f32)); return;
    }
    t -= 262144;
    if (t < 768){ return; }
    t -= 768;
    if (t < 512){
        float v;
        if (t < 256) v = ldin(cb, t, f32);
        else { int u_ = t - 256; int tt = u_ >> 4, nn = u_ & 15;
               int f = 2*((tt>>1)*16 + nn) + (tt & 1); v = ldin(fb, f, f32); }
        cbp[t] = v; return;
    }
    t -= 512;
    if (t < 4096){
        // dest: [ks 8][lm 16][quad 4][jj 8]; k-rows permuted by pm (layer-3 output perm)
        int ks = t >> 9, rem = t & 511;
        int lm = rem >> 5, r2 = rem & 31, quad = r2 >> 3, jj = r2 & 7;
        int kp = ks*32 + quad*8 + jj;
        int kl = pminv(kp);
        w4p[t] = (lm < 3) ? f2bf(ldin(iw4, lm*256 + kl, f32)) : (u16)0;
        return;
    }
    t -= 4096;
    if (t < 8192){
        // conv1 swizzle: [h 2][nt 4][ks 2][512]; K layout ks0: jr0@0..15, jr1@16..31; ks1: jr2@0..11
        int c = t >> 9, rem = t & 511;
        int lm = rem >> 5, r2 = rem & 31, quad = r2 >> 3, jj = r2 & 7;
        int h = c >> 3, nt = (c & 7) >> 1, ks = c & 1;
        int ch = h*64 + nt*16 + lm;
        int kk = quad*8 + jj;
        u16 v = 0;
        int jr = -1, r = 0;
        if (ks == 0){ jr = kk >> 4; r = kk & 15; }
        else if (kk < 16){ jr = 2; r = kk; }
        if (jr >= 0 && r < 12){
            int px = r >> 2, ci = r & 3;
            if (ci < 3) v = f2bf(ldin(a1w, ch*27 + ci*9 + jr*3 + px, f32));
        }
        w1sw[t] = v; return;
    }
    t -= 8192;
    if (t < 18432){
        // conv2 swizzle: [h 2][tap 9][ks 2][512]; k = ch within half
        int c = t >> 9, rem = t & 511;
        int lm = rem >> 5, r2 = rem & 31, quad = r2 >> 3, jj = r2 & 7;
        int h = c / 18, tap = (c % 18) >> 1, ks = c & 1;
        int k = ks*32 + quad*8 + jj;
        int ch = h*64 + k;
        u16 v = 0;
        if (lm < 3) v = f2bf(ldin(a2w, lm*1152 + ch*9 + tap, f32));
        w2sw[t] = v; return;
    }
}

// ---------------- MFMA adapter: conv1(3->128)+sin, conv2(128->3)+sin, build feat16 ----------------
__global__ __launch_bounds__(256, 3) void k_adapter(const void* __restrict__ inp, const void* __restrict__ score,
                                                    const void* __restrict__ cellp, char* __restrict__ ws){
    __shared__ __attribute__((aligned(16))) char smem[46480];
    bool f32 = is_f32(cellp);
    const float* a1bf = (const float*)(ws + A1B_OFF);
    const float* a2bf = (const float*)(ws + A2B_OFF);
    const u16*   w1sw = (const u16*)(ws + W1SW_OFF);
    const u16*   w2sw = (const u16*)(ws + W2SW_OFF);
    u16* feat16 = (u16*)(ws + FEAT16_OFF);

    int blk = blockIdx.x; int b = blk/288; int rem = blk%288;
    int ty0 = (rem/12)*8, tx0 = (rem%12)*16;
    int tid = threadIdx.x;
    u16* S   = (u16*)smem;
    u16* A   = (u16*)(smem + 1920);
    u16* hid = (u16*)(smem + 22000);

    if (tid < 240) ((u64*)smem)[tid] = 0ULL;
    __syncthreads();
    #pragma unroll 1
    for (int e = tid; e < 720; e += 256){
        int ci = e/240, r2 = e%240, hy = r2/20, hx = r2%20;
        int gy = ty0 - 2 + hy, gx = tx0 - 2 + hx;
        if (gy >= 0 && gy < 192 && gx >= 0 && gx < 192)
            S[(hy*20+hx)*4 + ci] = f2bf(ldin(inp, (b*3+ci)*36864 + gy*192 + gx, f32));
    }
    __syncthreads();
    #pragma unroll 1
    for (int p = tid; p < 193; p += 256){
        u64* drow = (u64*)(A + p*52);
        if (p < 180){
            int hy = p/18, hx = p%18;
            #pragma unroll
            for (int jr = 0; jr < 3; ++jr){
                const u64* srow = (const u64*)(S + ((hy+jr)*20 + hx)*4);
                u64 v0 = srow[0], v1 = srow[1], v2 = srow[2];
                drow[jr*4+0] = v0; drow[jr*4+1] = v1; drow[jr*4+2] = v2; drow[jr*4+3] = 0ULL;
            }
            drow[12] = 0ULL;
        } else {
            #pragma unroll
            for (int k = 0; k < 13; ++k) drow[k] = 0ULL;
        }
    }
    __syncthreads();

    const int wv = tid >> 6, ln = tid & 63;
    const int lm = ln & 15, quad = ln >> 4;
    const int laneoff = lm*32 + quad*8;

    float bias2 = (lm < 3) ? a2bf[lm] : 0.f;
    v4f acc2[2];
    acc2[0] = (v4f){bias2,bias2,bias2,bias2};
    acc2[1] = acc2[0];

    #pragma unroll 1
    for (int h = 0; h < 2; ++h){
        float bias1 = a1bf[h*64 + wv*16 + lm];
        v8s B0 = *(const v8s*)(w1sw + (h*8 + wv*2 + 0)*512 + laneoff);
        v8s B1 = *(const v8s*)(w1sw + (h*8 + wv*2 + 1)*512 + laneoff);
        #pragma unroll 4
        for (int mt = 0; mt < 12; ++mt){
            const u16* ar = A + (mt*16 + lm)*52 + quad*8;
            v8s a0 = *(const v8s*)(ar);
            v8s a1 = *(const v8s*)(ar + 32);
            v4f c = (v4f){bias1,bias1,bias1,bias1};
            c = __builtin_amdgcn_mfma_f32_16x16x32_bf16(a0, B0, c, 0,0,0);
            c = __builtin_amdgcn_mfma_f32_16x16x32_bf16(a1, B1, c, 0,0,0);
            #pragma unroll
            for (int r = 0; r < 4; ++r){
                int px = mt*16 + quad*4 + r;
                if (px < 180){
                    int hy = px/18, hx = px - hy*18;
                    int gy = ty0 - 1 + hy, gx = tx0 - 1 + hx;
                    bool ok = (gy >= 0) & (gy < 192) & (gx >= 0) & (gx < 192);
                    hid[px*68 + wv*16 + lm] = ok ? f2bf(__sinf(c[r])) : (u16)0;
                }
            }
        }
        __syncthreads();
        #pragma unroll 2
        for (int tap = 0; tap < 9; ++tap){
            int ty = tap/3, tx = tap%3;
            v8s Bt0 = *(const v8s*)(w2sw + ((h*9 + tap)*2 + 0)*512 + laneoff);
            v8s Bt1 = *(const v8s*)(w2sw + ((h*9 + tap)*2 + 1)*512 + laneoff);
            #pragma unroll
            for (int i = 0; i < 2; ++i){
                int py = wv*2 + i;
                const u16* hrow = hid + ((py+ty)*18 + lm + tx)*68;
                v8s a0 = *(const v8s*)(hrow + quad*8);
                v8s a1 = *(const v8s*)(hrow + 32 + quad*8);
                acc2[i] = __builtin_amdgcn_mfma_f32_16x16x32_bf16(a0, Bt0, acc2[i], 0,0,0);
                acc2[i] = __builtin_amdgcn_mfma_f32_16x16x32_bf16(a1, Bt1, acc2[i], 0,0,0);
            }
        }
        __syncthreads();
    }
    u16* out3 = S;
    if (lm < 3){
        #pragma unroll
        for (int i = 0; i < 2; ++i)
            #pragma unroll
            for (int r = 0; r < 4; ++r){
                int m = (wv*2 + i)*16 + quad*4 + r;
                out3[m*4 + lm] = f2bf(__sinf(acc2[i][r]));
            }
    }
    __syncthreads();
    if (tid < 128){
        int py = tid >> 4, px = tid & 15;
        int gy = ty0 + py, gx = tx0 + px;
        int pi = b*3*36864 + gy*192 + gx;
        v8u lo, hi;
        lo[0] = f2bf(ldin(inp, pi, f32));
        lo[1] = f2bf(ldin(inp, pi + 36864, f32));
        lo[2] = f2bf(ldin(inp, pi + 2*36864, f32));
        lo[3] = f2bf(ldin(score, pi, f32));
        lo[4] = f2bf(ldin(score, pi + 36864, f32));
        lo[5] = f2bf(ldin(score, pi + 2*36864, f32));
        lo[6] = out3[tid*4 + 0];
        lo[7] = out3[tid*4 + 1];
        hi[0] = out3[tid*4 + 2];
        hi[1]=hi[2]=hi[3]=hi[4]=hi[5]=hi[6]=hi[7]=0;
        u16* fp = feat16 + ((b*192 + gy)*192 + gx)*16;
        *(v8u*)fp = lo;
        *(v8u*)(fp + 8) = hi;
    }
}

// ---------------- mega kernel ----------------
// LDS 33792B: X [0,32768) swizzled (32 chunks of [64 q][16B], chunk C element q at q^(C&3));
// meta [32768,33792) [64]float4 (computed in phase 1, read by all phases — LOW REG PRESSURE:
// R7-R9 register-meta caused scratch spills, FETCH/WRITE +40/+66MB); Apat aliased X[0,12288).
// Columns physically permuted (p0 layer-0, pm between layers); W k-rows pre-permuted in k_pack.
// (256,3): per-SIMD VGPR pool 512 -> 170/wave at 3 waves/EU; (256,4)+ spills (R7/R8 evidence).
__global__ __launch_bounds__(256, 3) void k_mega(const char* __restrict__ ws,
                                                 const void* __restrict__ inp,
                                                 const void* __restrict__ coord,
                                                 const void* __restrict__ cellp,
                                                 void* __restrict__ out){
    __shared__ __attribute__((aligned(16))) char smem[33792];
    bool f32 = is_f32(cellp);
    const u16*   feat16 = (const u16*)(ws + FEAT16_OFF);
    const u16*   w2p    = (const u16*)(ws + W2P_OFF);
    const float* pwf    = (const float*)(ws + PWF_OFF);
    const float* ibf    = (const float*)(ws + IBF_OFF);
    const u16*   iwc    = (const u16*)(ws + IWC_OFF);
    const float* cbp    = (const float*)(ws + CBP_OFF);
    const u16*   w4p    = (const u16*)(ws + W4P_OFF);

    const int tid = threadIdx.x;
    const int qg0 = blockIdx.x * 64;
    const int b = qg0 / 36864;

    // ---- phase 1: gather patches into Apat (aliased at smem[0,12288)) + meta -> LDS ----
    {
        int q = tid >> 2, j = tid & 3;
        int qg = qg0 + q;
        u16* ap = (u16*)smem;
        float c0 = ldin(coord, qg*2, f32), c1 = ldin(coord, qg*2+1, f32);
        const float e = 1e-6f;
        float cy = fminf(fmaxf(c0, -1.f+e), 1.f-e);
        float cx = fminf(fmaxf(c1, -1.f+e), 1.f-e);
        int iy = (int)rintf(((cy+1.f)*192.f-1.f)*0.5f); iy = min(max(iy,0),191);
        int ix = (int)rintf(((cx+1.f)*192.f-1.f)*0.5f); ix = min(max(ix,0),191);
        if (j < 3){
            int yy = iy - 1 + j;
            bool yok = (yy >= 0) & (yy <= 191);
            union { u16 a[32]; v8u v[4]; } buf;
            #pragma unroll
            for (int c = 0; c < 32; ++c) buf.a[c] = 0;
            if (yok){
                const u16* base = feat16 + ((b*192 + yy)*192)*16;
                #pragma unroll
                for (int pix = 0; pix < 3; ++pix){
                    int xx = ix - 1 + pix;
                    if (xx >= 0 && xx <= 191){
                        const u16* s = base + xx*16;
                        v8u v = *(const v8u*)s;
                        u16 c8 = s[8];
                        #pragma unroll
                        for (int c = 0; c < 8; ++c) buf.a[pix*9+c] = v[c];
                        buf.a[pix*9+8] = c8;
                    }
                }
            }
            u16* dst = ap + q*96 + j*32;
            *(v8u*)(dst)      = buf.v[0];
            *(v8u*)(dst + 8)  = buf.v[1];
            *(v8u*)(dst + 16) = buf.v[2];
            *(v8u*)(dst + 24) = buf.v[3];
        } else {
            float qy = -1.f + (2.f*iy + 1.f)/192.f;
            float qx = -1.f + (2.f*ix + 1.f)/192.f;
            float4 mmv;
            mmv.x = (c0 - qy)*192.f; mmv.y = (c1 - qx)*192.f;
            mmv.z = ldin(cellp, qg*2, f32)*192.f; mmv.w = ldin(cellp, qg*2+1, f32)*192.f;
            ((float4*)(smem + 32768))[q] = mmv;
        }
    }
    __syncthreads();

    const int wv = tid >> 6, ln = tid & 63;
    const int lm = ln & 15, quad = ln >> 4;
    const int laneoff = lm*32 + quad*8;
    u32* X32 = (u32*)smem;

    // ---- phase 2+3: wave-owns-rows MFMA1, fused trig+modulation, packed u32 X writes ----
    {
        v8s afr[3];
        #pragma unroll
        for (int ks = 0; ks < 3; ++ks)
            afr[ks] = *(const v8s*)(smem + ((wv*16 + lm)*96 + ks*32 + quad*8)*2);
        float4 mm[4];
        #pragma unroll
        for (int r = 0; r < 4; ++r)
            mm[r] = ((const float4*)(smem + 32768))[wv*16 + quad*4 + r];
        float p0[8], p1[8];
        #pragma unroll
        for (int g = 0; g < 8; ++g){
            int j = g*16 + lm;
            p0[g] = pwf[2*j]; p1[g] = pwf[2*j+1];
        }
        v8s Bc0[3], Bc1[3], Bf0[3], Bf1[3];
        {
            const u16* p;
            p = w2p + 0*1536  + laneoff; Bc0[0]=*(const v8s*)p; Bc0[1]=*(const v8s*)(p+512); Bc0[2]=*(const v8s*)(p+1024);
            p = w2p + 8*1536  + laneoff; Bc1[0]=*(const v8s*)p; Bc1[1]=*(const v8s*)(p+512); Bc1[2]=*(const v8s*)(p+1024);
            p = w2p + 16*1536 + laneoff; Bf0[0]=*(const v8s*)p; Bf0[1]=*(const v8s*)(p+512); Bf0[2]=*(const v8s*)(p+1024);
            p = w2p + 17*1536 + laneoff; Bf1[0]=*(const v8s*)p; Bf1[1]=*(const v8s*)(p+512); Bf1[2]=*(const v8s*)(p+1024);
        }
        __syncthreads();   // Apat consumed by all waves; X region free for writes
        #pragma unroll 1
        for (int g = 0; g < 8; ++g){
            float bb0 = cbp[g*16+lm], bb1 = cbp[(8+g)*16+lm];
            float bb2 = cbp[(16+2*g)*16+lm], bb3 = cbp[(17+2*g)*16+lm];
            v4f a0 = (v4f){bb0,bb0,bb0,bb0};
            v4f a1 = (v4f){bb1,bb1,bb1,bb1};
            v4f a2 = (v4f){bb2,bb2,bb2,bb2};
            v4f a3 = (v4f){bb3,bb3,bb3,bb3};
            #pragma unroll
            for (int ks = 0; ks < 3; ++ks){
                a0 = __builtin_amdgcn_mfma_f32_16x16x32_bf16(afr[ks], Bc0[ks], a0, 0,0,0);
                a1 = __builtin_amdgcn_mfma_f32_16x16x32_bf16(afr[ks], Bc1[ks], a1, 0,0,0);
                a2 = __builtin_amdgcn_mfma_f32_16x16x32_bf16(afr[ks], Bf0[ks], a2, 0,0,0);
                a3 = __builtin_amdgcn_mfma_f32_16x16x32_bf16(afr[ks], Bf1[ks], a3, 0,0,0);
            }
            if (g < 7){
                const u16* p;
                p = w2p + (g+1)*1536    + laneoff; Bc0[0]=*(const v8s*)p; Bc0[1]=*(const v8s*)(p+512); Bc0[2]=*(const v8s*)(p+1024);
                p = w2p + (9+g)*1536    + laneoff; Bc1[0]=*(const v8s*)p; Bc1[1]=*(const v8s*)(p+512); Bc1[2]=*(const v8s*)(p+1024);
                p = w2p + (18+2*g)*1536 + laneoff; Bf0[0]=*(const v8s*)p; Bf0[1]=*(const v8s*)(p+512); Bf0[2]=*(const v8s*)(p+1024);
                p = w2p + (19+2*g)*1536 + laneoff; Bf1[0]=*(const v8s*)p; Bf1[1]=*(const v8s*)(p+512); Bf1[2]=*(const v8s*)(p+1024);
            }
            // X write: logical cols j (coef*cos), 128+j (coef*sin) -> phys 2j, 2j+1 packed u32
            int c2 = g*16 + lm;            // u32 column index
            int C = c2 >> 2, sw = lm >> 2; // C&3 == lm>>2
            int abase = C*256 + (lm & 3);
            #pragma unroll
            for (int r = 0; r < 4; ++r){
                float qf = a2[r]*mm[r].x + a3[r]*mm[r].y + mm[r].z*p0[g] + mm[r].w*p1[g];
                float sn, cs;
                __sincosf(PI_F * qf, &sn, &cs);
                int q = wv*16 + quad*4 + r;
                u32 val = (u32)f2bf(a0[r] * cs) | ((u32)f2bf(a1[r] * sn) << 16);
                X32[abase + ((q ^ sw) << 2)] = val;
            }
        }
    }
    __syncthreads();

    // ---- phase 5: 4 hidden layers 256->256 + relu, in-place X, depth-2 W prefetch ----
    #pragma unroll 1
    for (int l = 0; l < 4; ++l){
        const u16* Wb = iwc + (l*4 + wv)*16384 + laneoff;
        v4f acc[4][4];
        #pragma unroll
        for (int nt = 0; nt < 4; ++nt){
            float bv = ibf[l*256 + wv*64 + nt*16 + lm];
            #pragma unroll
            for (int mt = 0; mt < 4; ++mt) acc[nt][mt] = (v4f){bv,bv,bv,bv};
        }
        v8s bw[2][4];
        #pragma unroll
        for (int nt = 0; nt < 4; ++nt){
            bw[0][nt] = *(const v8s*)(Wb + (0*4 + nt)*512);
            bw[1][nt] = *(const v8s*)(Wb + (1*4 + nt)*512);
        }
        #pragma unroll
        for (int ks = 0; ks < 8; ++ks){
            v8s a[4];
            #pragma unroll
            for (int mt = 0; mt < 4; ++mt)
                a[mt] = *(const v8s*)((const char*)smem +
                        ((((ks*4 + quad)*64) + ((mt*16 + lm) ^ quad)) << 4));
            v8s nb[4];
            if (ks < 6){
                #pragma unroll
                for (int nt = 0; nt < 4; ++nt)
                    nb[nt] = *(const v8s*)(Wb + ((ks+2)*4 + nt)*512);
            }
            #pragma unroll
            for (int nt = 0; nt < 4; ++nt)
                #pragma unroll
                for (int mt = 0; mt < 4; ++mt)
                    acc[nt][mt] = __builtin_amdgcn_mfma_f32_16x16x32_bf16(a[mt], bw[ks&1][nt], acc[nt][mt], 0,0,0);
            if (ks < 6){
                #pragma unroll
                for (int nt = 0; nt < 4; ++nt) bw[ks&1][nt] = nb[nt];
            }
        }
        __syncthreads();   // all reads of X complete
        // epilogue: pm-permuted packed u32 writes (nt pairs interleaved)
        #pragma unroll
        for (int h = 0; h < 2; ++h){
            int c2 = wv*32 + h*16 + lm;
            int C = c2 >> 2, sw = lm >> 2;   // C&3 == lm>>2
            int abase = C*256 + (lm & 3);
            #pragma unroll
            for (int mt = 0; mt < 4; ++mt)
                #pragma unroll
                for (int r = 0; r < 4; ++r){
                    int q = mt*16 + quad*4 + r;
                    u32 lo16 = f2bf(fmaxf(acc[2*h+0][mt][r], 0.f));
                    u32 hi16 = f2bf(fmaxf(acc[2*h+1][mt][r], 0.f));
                    X32[abase + ((q ^ sw) << 2)] = lo16 | (hi16 << 16);
                }
        }
        __syncthreads();
    }

    // ---- phase 6: final 256->3 via MFMA (wave = row-tile) + bilinear ----
    {
        float bv = (lm < 3) ? ibf[1024 + lm] : 0.f;
        v4f accf = (v4f){bv,bv,bv,bv};
        v8s bA = *(const v8s*)(w4p + laneoff);
        #pragma unroll
        for (int ks = 0; ks < 8; ++ks){
            v8s a = *(const v8s*)((const char*)smem +
                    ((((ks*4 + quad)*64) + ((wv*16 + lm) ^ quad)) << 4));
            v8s bN;
            if (ks < 7) bN = *(const v8s*)(w4p + (ks+1)*512 + laneoff);
            accf = __builtin_amdgcn_mfma_f32_16x16x32_bf16(a, bA, accf, 0,0,0);
            bA = bN;
        }
        if (lm < 3){
            #pragma unroll
            for (int r = 0; r < 4; ++r){
                int q = wv*16 + quad*4 + r;
                int qg = qg0 + q;
                float c0 = ldin(coord, qg*2, f32), c1 = ldin(coord, qg*2+1, f32);
                float fy = ((c0 + 1.f)*192.f - 1.f)*0.5f;
                float fx = ((c1 + 1.f)*192.f - 1.f)*0.5f;
                float y0 = floorf(fy), x0 = floorf(fx);
                float wy = fy - y0, wx = fx - x0;
                int y0i = (int)fminf(fmaxf(y0, 0.f), 191.f);
                int y1i = (int)fminf(fmaxf(y0 + 1.f, 0.f), 191.f);
                int x0i = (int)fminf(fmaxf(x0, 0.f), 191.f);
                int x1i = (int)fminf(fmaxf(x0 + 1.f, 0.f), 191.f);
                int ibase = (b*3 + lm)*36864;
                float v00 = ldin(inp, ibase + y0i*192 + x0i, f32);
                float v01 = ldin(inp, ibase + y0i*192 + x1i, f32);
                float v10 = ldin(inp, ibase + y1i*192 + x0i, f32);
                float v11 = ldin(inp, ibase + y1i*192 + x1i, f32);
                float bil = v00*(1.f-wy)*(1.f-wx) + v01*(1.f-wy)*wx + v10*wy*(1.f-wx) + v11*wy*wx;
                float val = accf[r] + bil;
                if (f32) ((float*)out)[qg*3 + lm] = val;
                else     ((u16*)out)[qg*3 + lm] = f2bf(val);
            }
        }
    }
}

extern "C" void kernel_launch(void* const* d_in, const int* in_sizes, int n_in,
                              void* d_out, int out_size, void* d_ws, size_t ws_size,
                              hipStream_t stream){
    (void)in_sizes; (void)n_in; (void)out_size; (void)ws_size;
    const void* inp   = d_in[0];
    const void* score = d_in[1];
    const void* coord = d_in[2];
    const void* cellp = d_in[3];
    const void* cw    = d_in[4];
    const void* cb    = d_in[5];
    const void* fw    = d_in[6];
    const void* fb    = d_in[7];
    const void* pw    = d_in[8];
    const void* a1w   = d_in[9];
    const void* a1b   = d_in[10];
    const void* a2w   = d_in[11];
    const void* a2b   = d_in[12];
    const void* iw0   = d_in[13];
    const void* ib0   = d_in[14];
    const void* iw1   = d_in[15];
    const void* ib1   = d_in[16];
    const void* iw2   = d_in[17];
    const void* ib2   = d_in[18];
    const void* iw3   = d_in[19];
    const void* ib3   = d_in[20];
    const void* iw4   = d_in[21];
    const void* ib4   = d_in[22];
    char* ws = (char*)d_ws;

    hipLaunchKernelGGL(k_pack, dim3(1374), dim3(256), 0, stream,
                       cw, fw, a1w, a1b, a2w, a2b, cb, fb, pw,
                       iw0, ib0, iw1, ib1, iw2, ib2, iw3, ib3, iw4, ib4,
                       cellp, ws);
    hipLaunchKernelGGL(k_adapter, dim3(1152), dim3(256), 0, stream, inp, score, cellp, ws);
    hipLaunchKernelGGL(k_mega, dim3(2304), dim3(256), 0, stream, (const char*)ws, inp, coord, cellp, d_out);
}

// Round 11
// 312.518 us; speedup vs baseline: 1.1471x; 1.1022x over previous
//
#include <hip/hip_runtime.h>

typedef unsigned short u16;
typedef unsigned int   u32;
typedef unsigned long long u64;
typedef __attribute__((ext_vector_type(8))) short v8s;   // MFMA bf16 fragment
typedef __attribute__((ext_vector_type(8))) unsigned short v8u;
typedef __attribute__((ext_vector_type(4))) float v4f;

#define PI_F 3.14159265358979323846f

__device__ __forceinline__ float bf2f(u16 v){ u32 u = ((u32)v) << 16; return __builtin_bit_cast(float, u); }
__device__ __forceinline__ u16 f2bf(float f){
    u32 u = __builtin_bit_cast(u32, f);
    u32 r = (u + 0x7fffu + ((u >> 16) & 1u)) >> 16;
    return (u16)r;
}
// dtype discriminator: cell[0]=cell[1]=2/192. bf16 buffer -> first u32 halves equal.
__device__ __forceinline__ bool is_f32(const void* cellp){
    u32 u = *(const u32*)cellp;
    return ((u >> 16) != (u & 0xffffu));
}
__device__ __forceinline__ float ldin(const void* p, int i, bool f32){
    return f32 ? ((const float*)p)[i] : bf2f(((const u16*)p)[i]);
}

// ---------------- workspace layout (bytes), total 5,440,000 ----------------
// MFMA weight streams pre-swizzled to wave-order 512-u16 chunks: lane offset lm*32+quad*8.
#define FEAT16_OFF 0        // [4][192][192][16] bf16 (9 used + 7 pad)  4,718,592
#define W2P_OFF   4718592   // [32 tiles][3 ks][512] bf16 swizzled MFMA1 W (98,304)
#define A1W_OFF   4816896   // [128][27] f32 (legacy, unused)
#define A1B_OFF   4830720   // [128] f32
#define A2W_OFF   4831232   // [3][9][128] f32 (legacy, unused)
#define A2B_OFF   4845056   // [3] f32 (pad)
#define PWF_OFF   4845312   // [128][2] f32 phase w
#define IBF_OFF   4846336   // [1027] f32 ib0..ib3 | ib4 (pad)
#define IWC_OFF   4850688   // [4 layer][4 wv][8 ks][4 nt][512] bf16 swizzled MLP W (524,288)
#define CBP_OFF   5376512   // [512] f32 permuted-col bias for MFMA1
#define W4P_OFF   5378560   // [8 ks][512] bf16 swizzled final-layer W (8,192)
#define W1SW_OFF  5386752   // [2 h][4 nt][2 ks][512] bf16 swizzled conv1 W (16,384)
#define W2SW_OFF  5403136   // [2 h][9 tap][2 ks][512] bf16 swizzled conv2 W (36,864)

// ---------------- pack/convert kernel (dtype-adaptive) ----------------
__global__ __launch_bounds__(256) void k_pack(
    const void* cw, const void* fw, const void* a1w, const void* a1b,
    const void* a2w, const void* a2b, const void* cb, const void* fb, const void* pwp,
    const void* iw0, const void* ib0, const void* iw1, const void* ib1,
    const void* iw2, const void* ib2, const void* iw3, const void* ib3,
    const void* iw4, const void* ib4, const void* cellp, char* ws){
    bool f32 = is_f32(cellp);
    u16*   w2p  = (u16*)(ws + W2P_OFF);
    float* a1wf = (float*)(ws + A1W_OFF);
    float* a1bf = (float*)(ws + A1B_OFF);
    float* a2wf = (float*)(ws + A2W_OFF);
    float* a2bf = (float*)(ws + A2B_OFF);
    float* pwf  = (float*)(ws + PWF_OFF);
    float* ibf  = (float*)(ws + IBF_OFF);
    u16*   iwc  = (u16*)(ws + IWC_OFF);
    float* cbp  = (float*)(ws + CBP_OFF);
    u16*   w4p  = (u16*)(ws + W4P_OFF);
    u16*   w1sw = (u16*)(ws + W1SW_OFF);
    u16*   w2sw = (u16*)(ws + W2SW_OFF);

    int t = blockIdx.x*256 + threadIdx.x;
    if (t < 49152){
        // dest: [tile 32][ks 3][lm 16][quad 4][jj 8]
        int c = t >> 9, rem = t & 511;
        int tile = c/3, ks = c%3;
        int lm = rem >> 5, r2 = rem & 31, quad = r2 >> 3, jj = r2 & 7;
        int n = tile*16 + lm;          // permuted column
        int r = quad*8 + jj;           // k within row-chunk: 27 used + 5 pad
        u16 v = 0;
        if (r < 27){
            int pix = r/9, ch = r%9;
            int tap = ks*3 + pix;      // gather row ks, pixel pix
            int src = ch*9 + tap;
            if (n < 256) v = f2bf(ldin(cw, n*81 + src, f32));
            else { int u_ = n - 256; int tt = u_ >> 4, nn = u_ & 15;
                   int f = 2*((tt>>1)*16 + nn) + (tt & 1);
                   v = f2bf(ldin(fw, f*81 + src, f32)); }
        }
        w2p[t] = v; return;
    }
    t -= 49152;
    if (t < 3456){ a1wf[t] = ldin(a1w, t, f32); return; }
    t -= 3456;
    if (t < 128){ a1bf[t] = ldin(a1b, t, f32); return; }
    t -= 128;
    if (t < 3456){
        int o = t/1152, r = t%1152, c = r/9, tap = r%9;
        a2wf[(o*9 + tap)*128 + c] = ldin(a2w, t, f32); return;
    }
    t -= 3456;
    if (t < 3){ a2bf[t] = ldin(a2b, t, f32); return; }
    t -= 3;
    if (t < 256){ pwf[t] = ldin(pwp, t, f32); return; }
    t -= 256;
    if (t < 1027){
        const void* src = (t < 256) ? ib0 : (t < 512) ? ib1 : (t < 768) ? ib2 : (t < 1024) ? ib3 : ib4;
        int idx = (t < 1024) ? (t & 255) : (t - 1024);
        ibf[t] = ldin(src, idx, f32); return;
    }
    t -= 1027;
    if (t < 262144){
        // dest: [l 4][wv 4][ks 8][nt 4][lm 16][quad 4][jj 8] — straight k-rows
        int c = t >> 9, rem = t & 511;
        int lm = rem >> 5, r2 = rem & 31, quad = r2 >> 3, jj = r2 & 7;
        int nt = c & 3, ks = (c >> 2) & 7, wv = (c >> 5) & 3, l = c >> 7;
        int col = wv*64 + nt*16 + lm;
        int k = ks*32 + quad*8 + jj;
        const void* src = (l==0) ? iw0 : (l==1) ? iw1 : (l==2) ? iw2 : iw3;
        iwc[t] = f2bf(ldin(src, col*256 + k, f32)); return;
    }
    t -= 262144;
    if (t < 768){ return; }
    t -= 768;
    if (t < 512){
        float v;
        if (t < 256) v = ldin(cb, t, f32);
        else { int u_ = t - 256; int tt = u_ >> 4, nn = u_ & 15;
               int f = 2*((tt>>1)*16 + nn) + (tt & 1); v = ldin(fb, f, f32); }
        cbp[t] = v; return;
    }
    t -= 512;
    if (t < 4096){
        // dest: [ks 8][lm 16][quad 4][jj 8] — straight k-rows
        int ks = t >> 9, rem = t & 511;
        int lm = rem >> 5, r2 = rem & 31, quad = r2 >> 3, jj = r2 & 7;
        int k = ks*32 + quad*8 + jj;
        w4p[t] = (lm < 3) ? f2bf(ldin(iw4, lm*256 + k, f32)) : (u16)0;
        return;
    }
    t -= 4096;
    if (t < 8192){
        // conv1 swizzle: [h 2][nt 4][ks 2][512]; K layout ks0: jr0@0..15, jr1@16..31; ks1: jr2@0..11
        int c = t >> 9, rem = t & 511;
        int lm = rem >> 5, r2 = rem & 31, quad = r2 >> 3, jj = r2 & 7;
        int h = c >> 3, nt = (c & 7) >> 1, ks = c & 1;
        int ch = h*64 + nt*16 + lm;
        int kk = quad*8 + jj;
        u16 v = 0;
        int jr = -1, r = 0;
        if (ks == 0){ jr = kk >> 4; r = kk & 15; }
        else if (kk < 16){ jr = 2; r = kk; }
        if (jr >= 0 && r < 12){
            int px = r >> 2, ci = r & 3;
            if (ci < 3) v = f2bf(ldin(a1w, ch*27 + ci*9 + jr*3 + px, f32));
        }
        w1sw[t] = v; return;
    }
    t -= 8192;
    if (t < 18432){
        // conv2 swizzle: [h 2][tap 9][ks 2][512]; k = ch within half
        int c = t >> 9, rem = t & 511;
        int lm = rem >> 5, r2 = rem & 31, quad = r2 >> 3, jj = r2 & 7;
        int h = c / 18, tap = (c % 18) >> 1, ks = c & 1;
        int k = ks*32 + quad*8 + jj;
        int ch = h*64 + k;
        u16 v = 0;
        if (lm < 3) v = f2bf(ldin(a2w, lm*1152 + ch*9 + tap, f32));
        w2sw[t] = v; return;
    }
}

// ---------------- MFMA adapter: conv1(3->128)+sin, conv2(128->3)+sin, build feat16 ----------------
// Tile 16 wide x 8 tall. LDS: S (staged inp 12x20x4) [0,1920); A [1920,21992) im2col [193][52];
// hid [22000,46480) [180][68] (halo 18x10 x 64ch half). 3 blocks/CU.
__global__ __launch_bounds__(256, 3) void k_adapter(const void* __restrict__ inp, const void* __restrict__ score,
                                                    const void* __restrict__ cellp, char* __restrict__ ws){
    __shared__ __attribute__((aligned(16))) char smem[46480];
    bool f32 = is_f32(cellp);
    const float* a1bf = (const float*)(ws + A1B_OFF);
    const float* a2bf = (const float*)(ws + A2B_OFF);
    const u16*   w1sw = (const u16*)(ws + W1SW_OFF);
    const u16*   w2sw = (const u16*)(ws + W2SW_OFF);
    u16* feat16 = (u16*)(ws + FEAT16_OFF);

    int blk = blockIdx.x; int b = blk/288; int rem = blk%288;
    int ty0 = (rem/12)*8, tx0 = (rem%12)*16;
    int tid = threadIdx.x;
    u16* S   = (u16*)smem;
    u16* A   = (u16*)(smem + 1920);
    u16* hid = (u16*)(smem + 22000);

    if (tid < 240) ((u64*)smem)[tid] = 0ULL;
    __syncthreads();
    #pragma unroll 1
    for (int e = tid; e < 720; e += 256){
        int ci = e/240, r2 = e%240, hy = r2/20, hx = r2%20;
        int gy = ty0 - 2 + hy, gx = tx0 - 2 + hx;
        if (gy >= 0 && gy < 192 && gx >= 0 && gx < 192)
            S[(hy*20+hx)*4 + ci] = f2bf(ldin(inp, (b*3+ci)*36864 + gy*192 + gx, f32));
    }
    __syncthreads();
    #pragma unroll 1
    for (int p = tid; p < 193; p += 256){
        u64* drow = (u64*)(A + p*52);
        if (p < 180){
            int hy = p/18, hx = p%18;
            #pragma unroll
            for (int jr = 0; jr < 3; ++jr){
                const u64* srow = (const u64*)(S + ((hy+jr)*20 + hx)*4);
                u64 v0 = srow[0], v1 = srow[1], v2 = srow[2];
                drow[jr*4+0] = v0; drow[jr*4+1] = v1; drow[jr*4+2] = v2; drow[jr*4+3] = 0ULL;
            }
            drow[12] = 0ULL;
        } else {
            #pragma unroll
            for (int k = 0; k < 13; ++k) drow[k] = 0ULL;
        }
    }
    __syncthreads();

    const int wv = tid >> 6, ln = tid & 63;
    const int lm = ln & 15, quad = ln >> 4;
    const int laneoff = lm*32 + quad*8;

    float bias2 = (lm < 3) ? a2bf[lm] : 0.f;
    v4f acc2[2];
    acc2[0] = (v4f){bias2,bias2,bias2,bias2};
    acc2[1] = acc2[0];

    #pragma unroll 1
    for (int h = 0; h < 2; ++h){
        float bias1 = a1bf[h*64 + wv*16 + lm];
        v8s B0 = *(const v8s*)(w1sw + (h*8 + wv*2 + 0)*512 + laneoff);
        v8s B1 = *(const v8s*)(w1sw + (h*8 + wv*2 + 1)*512 + laneoff);
        #pragma unroll 4
        for (int mt = 0; mt < 12; ++mt){
            const u16* ar = A + (mt*16 + lm)*52 + quad*8;
            v8s a0 = *(const v8s*)(ar);
            v8s a1 = *(const v8s*)(ar + 32);
            v4f c = (v4f){bias1,bias1,bias1,bias1};
            c = __builtin_amdgcn_mfma_f32_16x16x32_bf16(a0, B0, c, 0,0,0);
            c = __builtin_amdgcn_mfma_f32_16x16x32_bf16(a1, B1, c, 0,0,0);
            #pragma unroll
            for (int r = 0; r < 4; ++r){
                int px = mt*16 + quad*4 + r;
                if (px < 180){
                    int hy = px/18, hx = px - hy*18;
                    int gy = ty0 - 1 + hy, gx = tx0 - 1 + hx;
                    bool ok = (gy >= 0) & (gy < 192) & (gx >= 0) & (gx < 192);
                    hid[px*68 + wv*16 + lm] = ok ? f2bf(__sinf(c[r])) : (u16)0;
                }
            }
        }
        __syncthreads();
        #pragma unroll 2
        for (int tap = 0; tap < 9; ++tap){
            int ty = tap/3, tx = tap%3;
            v8s Bt0 = *(const v8s*)(w2sw + ((h*9 + tap)*2 + 0)*512 + laneoff);
            v8s Bt1 = *(const v8s*)(w2sw + ((h*9 + tap)*2 + 1)*512 + laneoff);
            #pragma unroll
            for (int i = 0; i < 2; ++i){
                int py = wv*2 + i;
                const u16* hrow = hid + ((py+ty)*18 + lm + tx)*68;
                v8s a0 = *(const v8s*)(hrow + quad*8);
                v8s a1 = *(const v8s*)(hrow + 32 + quad*8);
                acc2[i] = __builtin_amdgcn_mfma_f32_16x16x32_bf16(a0, Bt0, acc2[i], 0,0,0);
                acc2[i] = __builtin_amdgcn_mfma_f32_16x16x32_bf16(a1, Bt1, acc2[i], 0,0,0);
            }
        }
        __syncthreads();
    }
    u16* out3 = S;
    if (lm < 3){
        #pragma unroll
        for (int i = 0; i < 2; ++i)
            #pragma unroll
            for (int r = 0; r < 4; ++r){
                int m = (wv*2 + i)*16 + quad*4 + r;
                out3[m*4 + lm] = f2bf(__sinf(acc2[i][r]));
            }
    }
    __syncthreads();
    if (tid < 128){
        int py = tid >> 4, px = tid & 15;
        int gy = ty0 + py, gx = tx0 + px;
        int pi = b*3*36864 + gy*192 + gx;
        v8u lo, hi;
        lo[0] = f2bf(ldin(inp, pi, f32));
        lo[1] = f2bf(ldin(inp, pi + 36864, f32));
        lo[2] = f2bf(ldin(inp, pi + 2*36864, f32));
        lo[3] = f2bf(ldin(score, pi, f32));
        lo[4] = f2bf(ldin(score, pi + 36864, f32));
        lo[5] = f2bf(ldin(score, pi + 2*36864, f32));
        lo[6] = out3[tid*4 + 0];
        lo[7] = out3[tid*4 + 1];
        hi[0] = out3[tid*4 + 2];
        hi[1]=hi[2]=hi[3]=hi[4]=hi[5]=hi[6]=hi[7]=0;
        u16* fp = feat16 + ((b*192 + gy)*192 + gx)*16;
        *(v8u*)fp = lo;
        *(v8u*)(fp + 8) = hi;
    }
}

// ---------------- mega kernel (R6-proven config: 173 us, VGPR 72, no spill) ----------------
// LDS 46080B: X [0,32768) k-blocked [8][64][32] u16 (in-place MLP);
//             Apat [32768,45056) [64][3*32] u16; meta [45056,46080) [64]float4
// NOTE (R7-R10 evidence): (256,4)+ spills (62-563MB scratch W); register-meta spills;
// X swizzle +12 VGPR also spills. This exact config is the no-spill optimum at (256,3).
__global__ __launch_bounds__(256, 3) void k_mega(const char* __restrict__ ws,
                                                 const void* __restrict__ inp,
                                                 const void* __restrict__ coord,
                                                 const void* __restrict__ cellp,
                                                 void* __restrict__ out){
    __shared__ __attribute__((aligned(16))) char smem[46080];
    bool f32 = is_f32(cellp);
    const u16*   feat16 = (const u16*)(ws + FEAT16_OFF);
    const u16*   w2p    = (const u16*)(ws + W2P_OFF);
    const float* pwf    = (const float*)(ws + PWF_OFF);
    const float* ibf    = (const float*)(ws + IBF_OFF);
    const u16*   iwc    = (const u16*)(ws + IWC_OFF);
    const float* cbp    = (const float*)(ws + CBP_OFF);
    const u16*   w4p    = (const u16*)(ws + W4P_OFF);

    const int tid = threadIdx.x;
    const int qg0 = blockIdx.x * 64;
    const int b = qg0 / 36864;

    {
        int q = tid >> 2, j = tid & 3;
        int qg = qg0 + q;
        u16* ap = (u16*)(smem + 32768);
        float c0 = ldin(coord, qg*2, f32), c1 = ldin(coord, qg*2+1, f32);
        const float e = 1e-6f;
        float cy = fminf(fmaxf(c0, -1.f+e), 1.f-e);
        float cx = fminf(fmaxf(c1, -1.f+e), 1.f-e);
        int iy = (int)rintf(((cy+1.f)*192.f-1.f)*0.5f); iy = min(max(iy,0),191);
        int ix = (int)rintf(((cx+1.f)*192.f-1.f)*0.5f); ix = min(max(ix,0),191);
        if (j < 3){
            int yy = iy - 1 + j;
            bool yok = (yy >= 0) & (yy <= 191);
            union { u16 a[32]; v8u v[4]; } buf;
            #pragma unroll
            for (int c = 0; c < 32; ++c) buf.a[c] = 0;
            if (yok){
                const u16* base = feat16 + ((b*192 + yy)*192)*16;
                #pragma unroll
                for (int pix = 0; pix < 3; ++pix){
                    int xx = ix - 1 + pix;
                    if (xx >= 0 && xx <= 191){
                        const u16* s = base + xx*16;
                        v8u v = *(const v8u*)s;
                        u16 c8 = s[8];
                        #pragma unroll
                        for (int c = 0; c < 8; ++c) buf.a[pix*9+c] = v[c];
                        buf.a[pix*9+8] = c8;
                    }
                }
            }
            u16* dst = ap + q*96 + j*32;
            *(v8u*)(dst)      = buf.v[0];
            *(v8u*)(dst + 8)  = buf.v[1];
            *(v8u*)(dst + 16) = buf.v[2];
            *(v8u*)(dst + 24) = buf.v[3];
        } else {
            float qy = -1.f + (2.f*iy + 1.f)/192.f;
            float qx = -1.f + (2.f*ix + 1.f)/192.f;
            float4 mmv;
            mmv.x = (c0 - qy)*192.f; mmv.y = (c1 - qx)*192.f;
            mmv.z = ldin(cellp, qg*2, f32)*192.f; mmv.w = ldin(cellp, qg*2+1, f32)*192.f;
            ((float4*)(smem + 45056))[q] = mmv;
        }
    }
    __syncthreads();

    const int wv = tid >> 6, ln = tid & 63;
    const int lm = ln & 15, quad = ln >> 4;
    const int laneoff = lm*32 + quad*8;
    u16* X = (u16*)smem;

    // ---- phase 2+3: wave-owns-rows MFMA1, fused trig+modulation ----
    {
        v8s afr[3];
        #pragma unroll
        for (int ks = 0; ks < 3; ++ks)
            afr[ks] = *(const v8s*)(smem + 32768 + ((wv*16 + lm)*96 + ks*32 + quad*8)*2);
        float4 mm[4];
        #pragma unroll
        for (int r = 0; r < 4; ++r)
            mm[r] = ((const float4*)(smem + 45056))[wv*16 + quad*4 + r];
        float p0[8], p1[8];
        #pragma unroll
        for (int g = 0; g < 8; ++g){
            int j = g*16 + lm;
            p0[g] = pwf[2*j]; p1[g] = pwf[2*j+1];
        }
        v8s Bc0[3], Bc1[3], Bf0[3], Bf1[3];
        {
            const u16* p;
            p = w2p + 0*1536  + laneoff; Bc0[0]=*(const v8s*)p; Bc0[1]=*(const v8s*)(p+512); Bc0[2]=*(const v8s*)(p+1024);
            p = w2p + 8*1536  + laneoff; Bc1[0]=*(const v8s*)p; Bc1[1]=*(const v8s*)(p+512); Bc1[2]=*(const v8s*)(p+1024);
            p = w2p + 16*1536 + laneoff; Bf0[0]=*(const v8s*)p; Bf0[1]=*(const v8s*)(p+512); Bf0[2]=*(const v8s*)(p+1024);
            p = w2p + 17*1536 + laneoff; Bf1[0]=*(const v8s*)p; Bf1[1]=*(const v8s*)(p+512); Bf1[2]=*(const v8s*)(p+1024);
        }
        #pragma unroll 1
        for (int g = 0; g < 8; ++g){
            float bb0 = cbp[g*16+lm], bb1 = cbp[(8+g)*16+lm];
            float bb2 = cbp[(16+2*g)*16+lm], bb3 = cbp[(17+2*g)*16+lm];
            v4f a0 = (v4f){bb0,bb0,bb0,bb0};
            v4f a1 = (v4f){bb1,bb1,bb1,bb1};
            v4f a2 = (v4f){bb2,bb2,bb2,bb2};
            v4f a3 = (v4f){bb3,bb3,bb3,bb3};
            #pragma unroll
            for (int ks = 0; ks < 3; ++ks){
                a0 = __builtin_amdgcn_mfma_f32_16x16x32_bf16(afr[ks], Bc0[ks], a0, 0,0,0);
                a1 = __builtin_amdgcn_mfma_f32_16x16x32_bf16(afr[ks], Bc1[ks], a1, 0,0,0);
                a2 = __builtin_amdgcn_mfma_f32_16x16x32_bf16(afr[ks], Bf0[ks], a2, 0,0,0);
                a3 = __builtin_amdgcn_mfma_f32_16x16x32_bf16(afr[ks], Bf1[ks], a3, 0,0,0);
            }
            if (g < 7){
                const u16* p;
                p = w2p + (g+1)*1536    + laneoff; Bc0[0]=*(const v8s*)p; Bc0[1]=*(const v8s*)(p+512); Bc0[2]=*(const v8s*)(p+1024);
                p = w2p + (9+g)*1536    + laneoff; Bc1[0]=*(const v8s*)p; Bc1[1]=*(const v8s*)(p+512); Bc1[2]=*(const v8s*)(p+1024);
                p = w2p + (18+2*g)*1536 + laneoff; Bf0[0]=*(const v8s*)p; Bf0[1]=*(const v8s*)(p+512); Bf0[2]=*(const v8s*)(p+1024);
                p = w2p + (19+2*g)*1536 + laneoff; Bf1[0]=*(const v8s*)p; Bf1[1]=*(const v8s*)(p+512); Bf1[2]=*(const v8s*)(p+1024);
            }
            int j = g*16 + lm;
            int koff_c = (j>>5)*2048 + (j&31);
            int koff_s = ((128+j)>>5)*2048 + (j&31);
            #pragma unroll
            for (int r = 0; r < 4; ++r){
                float qf = a2[r]*mm[r].x + a3[r]*mm[r].y + mm[r].z*p0[g] + mm[r].w*p1[g];
                float sn, cs;
                __sincosf(PI_F * qf, &sn, &cs);
                int q = wv*16 + quad*4 + r;
                X[koff_c + q*32] = f2bf(a0[r] * cs);
                X[koff_s + q*32] = f2bf(a1[r] * sn);
            }
        }
    }
    __syncthreads();

    // ---- phase 5: 4 hidden layers 256->256 + relu, in-place X, depth-2 W prefetch ----
    #pragma unroll 1
    for (int l = 0; l < 4; ++l){
        const u16* Wb = iwc + (l*4 + wv)*16384 + laneoff;
        v4f acc[4][4];
        #pragma unroll
        for (int nt = 0; nt < 4; ++nt){
            float bv = ibf[l*256 + wv*64 + nt*16 + lm];
            #pragma unroll
            for (int mt = 0; mt < 4; ++mt) acc[nt][mt] = (v4f){bv,bv,bv,bv};
        }
        v8s bw[2][4];
        #pragma unroll
        for (int nt = 0; nt < 4; ++nt){
            bw[0][nt] = *(const v8s*)(Wb + (0*4 + nt)*512);
            bw[1][nt] = *(const v8s*)(Wb + (1*4 + nt)*512);
        }
        #pragma unroll
        for (int ks = 0; ks < 8; ++ks){
            v8s a[4];
            #pragma unroll
            for (int mt = 0; mt < 4; ++mt)
                a[mt] = *(const v8s*)(smem + (ks*2048 + (mt*16 + lm)*32 + quad*8)*2);
            v8s nb[4];
            if (ks < 6){
                #pragma unroll
                for (int nt = 0; nt < 4; ++nt)
                    nb[nt] = *(const v8s*)(Wb + ((ks+2)*4 + nt)*512);
            }
            #pragma unroll
            for (int nt = 0; nt < 4; ++nt)
                #pragma unroll
                for (int mt = 0; mt < 4; ++mt)
                    acc[nt][mt] = __builtin_amdgcn_mfma_f32_16x16x32_bf16(a[mt], bw[ks&1][nt], acc[nt][mt], 0,0,0);
            if (ks < 6){
                #pragma unroll
                for (int nt = 0; nt < 4; ++nt) bw[ks&1][nt] = nb[nt];
            }
        }
        __syncthreads();
        #pragma unroll
        for (int nt = 0; nt < 4; ++nt){
            int col = wv*64 + nt*16 + lm;
            u16* base = X + (col>>5)*2048 + (col&31);
            #pragma unroll
            for (int mt = 0; mt < 4; ++mt)
                #pragma unroll
                for (int r = 0; r < 4; ++r){
                    int q = mt*16 + quad*4 + r;
                    base[q*32] = f2bf(fmaxf(acc[nt][mt][r], 0.f));
                }
        }
        __syncthreads();
    }

    // ---- phase 6: final 256->3 via MFMA (wave = row-tile) + bilinear ----
    {
        float bv = (lm < 3) ? ibf[1024 + lm] : 0.f;
        v4f accf = (v4f){bv,bv,bv,bv};
        v8s bA = *(const v8s*)(w4p + laneoff);
        #pragma unroll
        for (int ks = 0; ks < 8; ++ks){
            v8s a = *(const v8s*)(smem + (ks*2048 + (wv*16 + lm)*32 + quad*8)*2);
            v8s bN;
            if (ks < 7) bN = *(const v8s*)(w4p + (ks+1)*512 + laneoff);
            accf = __builtin_amdgcn_mfma_f32_16x16x32_bf16(a, bA, accf, 0,0,0);
            bA = bN;
        }
        if (lm < 3){
            #pragma unroll
            for (int r = 0; r < 4; ++r){
                int q = wv*16 + quad*4 + r;
                int qg = qg0 + q;
                float c0 = ldin(coord, qg*2, f32), c1 = ldin(coord, qg*2+1, f32);
                float fy = ((c0 + 1.f)*192.f - 1.f)*0.5f;
                float fx = ((c1 + 1.f)*192.f - 1.f)*0.5f;
                float y0 = floorf(fy), x0 = floorf(fx);
                float wy = fy - y0, wx = fx - x0;
                int y0i = (int)fminf(fmaxf(y0, 0.f), 191.f);
                int y1i = (int)fminf(fmaxf(y0 + 1.f, 0.f), 191.f);
                int x0i = (int)fminf(fmaxf(x0, 0.f), 191.f);
                int x1i = (int)fminf(fmaxf(x0 + 1.f, 0.f), 191.f);
                int ibase = (b*3 + lm)*36864;
                float v00 = ldin(inp, ibase + y0i*192 + x0i, f32);
                float v01 = ldin(inp, ibase + y0i*192 + x1i, f32);
                float v10 = ldin(inp, ibase + y1i*192 + x0i, f32);
                float v11 = ldin(inp, ibase + y1i*192 + x1i, f32);
                float bil = v00*(1.f-wy)*(1.f-wx) + v01*(1.f-wy)*wx + v10*wy*(1.f-wx) + v11*wy*wx;
                float val = accf[r] + bil;
                if (f32) ((float*)out)[qg*3 + lm] = val;
                else     ((u16*)out)[qg*3 + lm] = f2bf(val);
            }
        }
    }
}

extern "C" void kernel_launch(void* const* d_in, const int* in_sizes, int n_in,
                              void* d_out, int out_size, void* d_ws, size_t ws_size,
                              hipStream_t stream){
    (void)in_sizes; (void)n_in; (void)out_size; (void)ws_size;
    const void* inp   = d_in[0];
    const void* score = d_in[1];
    const void* coord = d_in[2];
    const void* cellp = d_in[3];
    const void* cw    = d_in[4];
    const void* cb    = d_in[5];
    const void* fw    = d_in[6];
    const void* fb    = d_in[7];
    const void* pw    = d_in[8];
    const void* a1w   = d_in[9];
    const void* a1b   = d_in[10];
    const void* a2w   = d_in[11];
    const void* a2b   = d_in[12];
    const void* iw0   = d_in[13];
    const void* ib0   = d_in[14];
    const void* iw1   = d_in[15];
    const void* ib1   = d_in[16];
    const void* iw2   = d_in[17];
    const void* ib2   = d_in[18];
    const void* iw3   = d_in[19];
    const void* ib3   = d_in[20];
    const void* iw4   = d_in[21];
    const void* ib4   = d_in[22];
    char* ws = (char*)d_ws;

    hipLaunchKernelGGL(k_pack, dim3(1374), dim3(256), 0, stream,
                       cw, fw, a1w, a1b, a2w, a2b, cb, fb, pw,
                       iw0, ib0, iw1, ib1, iw2, ib2, iw3, ib3, iw4, ib4,
                       cellp, ws);
    hipLaunchKernelGGL(k_adapter, dim3(1152), dim3(256), 0, stream, inp, score, cellp, ws);
    hipLaunchKernelGGL(k_mega, dim3(2304), dim3(256), 0, stream, (const char*)ws, inp, coord, cellp, d_out);
}